// Round 1
// baseline (3786.694 us; speedup 1.0000x reference)
//
#include <hip/hip_runtime.h>

#define DD 128
typedef unsigned int u32;

__device__ __forceinline__ u32 fmap(float f) {
  u32 u = __float_as_uint(f);
  return (u & 0x80000000u) ? ~u : (u | 0x80000000u);
}
__device__ __forceinline__ float funmap(u32 u) {
  return (u & 0x80000000u) ? __uint_as_float(u & 0x7FFFFFFFu) : __uint_as_float(~u);
}
__device__ __forceinline__ float lrelu(float v, float s) { return v >= 0.f ? v : s * v; }

// ---------------- h = x @ W ; el = (h*al).sum(-1) ; er = (h*ar).sum(-1) ----------------
// block 256 threads: c = t&127 (output column), g = t>>7 (node-group of 8). 16 nodes/block.
__global__ __launch_bounds__(256) void k_gemm_h(
    const float* __restrict__ x, const float* __restrict__ W,
    const float* __restrict__ al, const float* __restrict__ ar,
    float* __restrict__ h, float* __restrict__ el, float* __restrict__ er, int N)
{
  __shared__ __align__(16) float xs[16][DD];
  __shared__ float redl[16][2], redr[16][2];
  const int t = threadIdx.x;
  const int c = t & 127, g = t >> 7;
  const int n0 = blockIdx.x * 16;

  // stage 16 rows of x into LDS (float4, coalesced)
  for (int i = t; i < 16 * 32; i += 256) {
    int row = i >> 5, col4 = i & 31;
    int n = n0 + row;
    float4 v = make_float4(0.f, 0.f, 0.f, 0.f);
    if (n < N) v = *(const float4*)(x + (size_t)n * DD + col4 * 4);
    *(float4*)&xs[row][col4 * 4] = v;
  }
  __syncthreads();

  float acc[8];
#pragma unroll
  for (int j = 0; j < 8; j++) acc[j] = 0.f;
  const float* Wc = W + c;
  for (int k = 0; k < DD; k += 4) {
    float w0 = Wc[(size_t)k * DD];
    float w1 = Wc[(size_t)(k + 1) * DD];
    float w2 = Wc[(size_t)(k + 2) * DD];
    float w3 = Wc[(size_t)(k + 3) * DD];
#pragma unroll
    for (int j = 0; j < 8; j++) {
      float4 xv = *(const float4*)&xs[g * 8 + j][k];
      acc[j] = fmaf(xv.x, w0, fmaf(xv.y, w1, fmaf(xv.z, w2, fmaf(xv.w, w3, acc[j]))));
    }
  }

  const float alc = al[c], arc = ar[c];
#pragma unroll
  for (int j = 0; j < 8; j++) {
    int n = n0 + g * 8 + j;
    if (n < N) h[(size_t)n * DD + c] = acc[j];
    float vl = acc[j] * alc, vr = acc[j] * arc;
#pragma unroll
    for (int o = 32; o; o >>= 1) { vl += __shfl_xor(vl, o); vr += __shfl_xor(vr, o); }
    if ((t & 63) == 0) { int w = t >> 6; redl[g * 8 + j][w & 1] = vl; redr[g * 8 + j][w & 1] = vr; }
  }
  __syncthreads();
  if (t < 16) {
    int n = n0 + t;
    if (n < N) { el[n] = redl[t][0] + redl[t][1]; er[n] = redr[t][0] + redr[t][1]; }
  }
}

// ---------------- per-relation node state init ----------------
__global__ void k_init_node(u32* __restrict__ mmax, float* __restrict__ ssum, int N) {
  int i = blockIdx.x * 256 + threadIdx.x;
  if (i < N) { mmax[i] = 0x007FFFFFu; /* fmap(-inf) */ ssum[i] = 0.f; }
}

// ---------------- e = LReLU(el[src]+er[dst], 0.2); segment max over dst ----------------
__global__ void k_edge_emax(const int* __restrict__ src, const int* __restrict__ dst,
    const float* __restrict__ el, const float* __restrict__ er,
    float* __restrict__ ebuf, u32* __restrict__ mmax, int E)
{
  int i = blockIdx.x * 256 + threadIdx.x;
  if (i >= E) return;
  float e = el[src[i]] + er[dst[i]];
  e = lrelu(e, 0.2f);
  ebuf[i] = e;
  atomicMax(mmax + dst[i], fmap(e));
}

// ---------------- a = exp(e - m[dst]); segment sum ----------------
__global__ void k_edge_expsum(const int* __restrict__ dst,
    float* __restrict__ ebuf, const u32* __restrict__ mmax, float* __restrict__ ssum, int E)
{
  int i = blockIdx.x * 256 + threadIdx.x;
  if (i >= E) return;
  int d = dst[i];
  float a = __expf(ebuf[i] - funmap(mmax[d]));
  ebuf[i] = a;
  atomicAdd(ssum + d, a);
}

// ---------------- feats[dst] += (a/s[dst]*ew) * h[src]  (32 lanes/edge, float4) ----------------
__global__ void k_edge_agg(const int* __restrict__ src, const int* __restrict__ dst,
    const float* __restrict__ ew, const float* __restrict__ abuf,
    const float* __restrict__ ssum, const float* __restrict__ h,
    float* __restrict__ feats, int E)
{
  long long gid = (long long)blockIdx.x * 256 + threadIdx.x;
  int i = (int)(gid >> 5);
  if (i >= E) return;
  int q = (int)(gid & 31);
  int s = src[i], d = dst[i];
  float alpha = abuf[i] / ssum[d] * ew[i];
  float4 hv = *(const float4*)(h + (size_t)s * DD + q * 4);
  float* fp = feats + (size_t)d * DD + q * 4;
  atomicAdd(fp + 0, alpha * hv.x);
  atomicAdd(fp + 1, alpha * hv.y);
  atomicAdd(fp + 2, alpha * hv.z);
  atomicAdd(fp + 3, alpha * hv.w);
}

// ---------------- f = feats + bias; s += f; q += f*f; feats = 0 ----------------
__global__ void k_accum(float* __restrict__ feats, const float* __restrict__ b,
    float* __restrict__ sacc, float* __restrict__ qacc, long long ND4, int first)
{
  long long i = (long long)blockIdx.x * 256 + threadIdx.x;
  if (i >= ND4) return;
  float4* f4 = (float4*)feats;
  float4 f = f4[i];
  const float4 bb = *(const float4*)(b + ((i * 4) & 127));
  f.x += bb.x; f.y += bb.y; f.z += bb.z; f.w += bb.w;
  float4 sq = make_float4(f.x * f.x, f.y * f.y, f.z * f.z, f.w * f.w);
  float4* s4 = (float4*)sacc;
  float4* q4 = (float4*)qacc;
  if (first) { s4[i] = f; q4[i] = sq; }
  else {
    float4 s = s4[i], q = q4[i];
    s.x += f.x; s.y += f.y; s.z += f.z; s.w += f.w;
    q.x += sq.x; q.y += sq.y; q.z += sq.z; q.w += sq.w;
    s4[i] = s; q4[i] = q;
  }
  f4[i] = make_float4(0.f, 0.f, 0.f, 0.f);
}

// ---------------- transpose 128x128 weight ----------------
__global__ void k_transpose(const float* __restrict__ w, float* __restrict__ wt) {
  int i = blockIdx.x * 256 + threadIdx.x;  // 16384 total
  int c = i >> 7, k = i & 127;
  wt[k * DD + c] = w[i];
}

// ---------------- combine: dfm/s matvecs + leaky + residual + LayerNorm ----------------
// block 128 threads: t = output column. 8 nodes/block.
__global__ __launch_bounds__(128) void k_combine(
    const float* __restrict__ sacc, const float* __restrict__ qacc,
    const float* __restrict__ x,
    const float* __restrict__ biT, const float* __restrict__ siT,
    const float* __restrict__ bi_b, const float* __restrict__ si_b,
    const float* __restrict__ res_w, const float* __restrict__ ln_g,
    const float* __restrict__ ln_b,
    float* __restrict__ out, int N)
{
  __shared__ __align__(16) float st[DD][8], dt[DD][8];
  __shared__ float redm[8][2], redq[8][2];
  const int t = threadIdx.x;
  const int n0 = blockIdx.x * 8;

  for (int it = 0; it < 8; ++it) {
    int n = n0 + it;
    float s = 0.f, q = 0.f;
    if (n < N) { s = sacc[(size_t)n * DD + t]; q = qacc[(size_t)n * DD + t]; }
    st[t][it] = s;
    dt[t][it] = 0.5f * (s * s - q);
  }
  __syncthreads();

  float accB[8], accS[8];
#pragma unroll
  for (int j = 0; j < 8; j++) { accB[j] = 0.f; accS[j] = 0.f; }
  const float* bT = biT + t;
  const float* sT = siT + t;
  for (int k = 0; k < DD; k++) {
    float wb = bT[(size_t)k * DD];
    float ws = sT[(size_t)k * DD];
    float dv[8], sv[8];
    *(float4*)&dv[0] = *(const float4*)&dt[k][0];
    *(float4*)&dv[4] = *(const float4*)&dt[k][4];
    *(float4*)&sv[0] = *(const float4*)&st[k][0];
    *(float4*)&sv[4] = *(const float4*)&st[k][4];
#pragma unroll
    for (int j = 0; j < 8; j++) {
      accB[j] = fmaf(dv[j], wb, accB[j]);
      accS[j] = fmaf(sv[j], ws, accS[j]);
    }
  }

  const float sigw = 1.f / (1.f + __expf(-res_w[0]));
  const float bib = bi_b[t], sib = si_b[t], g = ln_g[t], bb = ln_b[t];
  float v[8];
#pragma unroll
  for (int j = 0; j < 8; j++) {
    int n = n0 + j;
    float xv = (n < N) ? x[(size_t)n * DD + t] : 0.f;
    float val = lrelu(accB[j] + bib, 0.01f) + lrelu(accS[j] + sib, 0.01f) + xv * sigw;
    v[j] = val;
    float sv = val, sq = val * val;
#pragma unroll
    for (int o = 32; o; o >>= 1) { sv += __shfl_xor(sv, o); sq += __shfl_xor(sq, o); }
    if ((t & 63) == 0) { redm[j][t >> 6] = sv; redq[j][t >> 6] = sq; }
  }
  __syncthreads();
#pragma unroll
  for (int j = 0; j < 8; j++) {
    int n = n0 + j;
    if (n >= N) continue;
    float mu = (redm[j][0] + redm[j][1]) * (1.f / DD);
    float ex2 = (redq[j][0] + redq[j][1]) * (1.f / DD);
    float var = ex2 - mu * mu;
    out[(size_t)n * DD + t] = (v[j] - mu) * rsqrtf(var + 1e-5f) * g + bb;
  }
}

extern "C" void kernel_launch(void* const* d_in, const int* in_sizes, int n_in,
                              void* d_out, int out_size, void* d_ws, size_t ws_size,
                              hipStream_t stream)
{
  const float* x    = (const float*)d_in[0];
  const int*   esrc = (const int*)d_in[1];
  const int*   edst = (const int*)d_in[2];
  const float* ew   = (const float*)d_in[3];
  const float* W    = (const float*)d_in[4];
  const float* al   = (const float*)d_in[5];
  const float* ar   = (const float*)d_in[6];
  const float* gb   = (const float*)d_in[7];
  const float* bi_w = (const float*)d_in[8];
  const float* bi_b = (const float*)d_in[9];
  const float* si_w = (const float*)d_in[10];
  const float* si_b = (const float*)d_in[11];
  const float* res_w= (const float*)d_in[12];
  const float* ln_g = (const float*)d_in[13];
  const float* ln_b = (const float*)d_in[14];

  const int N = in_sizes[0] / DD;
  const int R = 3;
  const int E = in_sizes[1] / R;
  const size_t ND = (size_t)N * DD;

  char* p = (char*)d_ws;
  float* h     = (float*)p; p += ND * 4;
  float* feats = (float*)p; p += ND * 4;
  float* sacc  = (float*)p; p += ND * 4;
  float* qacc  = (float*)p; p += ND * 4;
  float* el    = (float*)p; p += (size_t)N * 4;
  float* er    = (float*)p; p += (size_t)N * 4;
  u32*   mmax  = (u32*)p;  p += (size_t)N * 4;
  float* ssum  = (float*)p; p += (size_t)N * 4;
  float* ebuf  = (float*)p; p += (size_t)E * 4;
  float* biT   = (float*)p; p += (size_t)DD * DD * 4;
  float* siT   = (float*)p; p += (size_t)DD * DD * 4;

  hipMemsetAsync(feats, 0, ND * 4, stream);
  k_transpose<<<64, 256, 0, stream>>>(bi_w, biT);
  k_transpose<<<64, 256, 0, stream>>>(si_w, siT);

  for (int r = 0; r < R; r++) {
    k_gemm_h<<<(N + 15) / 16, 256, 0, stream>>>(
        x, W + (size_t)r * DD * DD, al + r * DD, ar + r * DD, h, el, er, N);
    k_init_node<<<(N + 255) / 256, 256, 0, stream>>>(mmax, ssum, N);
    k_edge_emax<<<(E + 255) / 256, 256, 0, stream>>>(
        esrc + (size_t)r * E, edst + (size_t)r * E, el, er, ebuf, mmax, E);
    k_edge_expsum<<<(E + 255) / 256, 256, 0, stream>>>(
        edst + (size_t)r * E, ebuf, mmax, ssum, E);
    k_edge_agg<<<(int)(((long long)E * 32 + 255) / 256), 256, 0, stream>>>(
        esrc + (size_t)r * E, edst + (size_t)r * E, ew + (size_t)r * E,
        ebuf, ssum, h, feats, E);
    k_accum<<<(int)((ND / 4 + 255) / 256), 256, 0, stream>>>(
        feats, gb + r * DD, sacc, qacc, (long long)(ND / 4), r == 0);
  }
  k_combine<<<(N + 7) / 8, 128, 0, stream>>>(
      sacc, qacc, x, biT, siT, bi_b, si_b, res_w, ln_g, ln_b, (float*)d_out, N);
}

// Round 2
// 1363.694 us; speedup vs baseline: 2.7768x; 2.7768x over previous
//
#include <hip/hip_runtime.h>

#define DD 128
typedef unsigned int u32;

__device__ __forceinline__ float lrelu(float v, float s) { return v >= 0.f ? v : s * v; }

// ---------------- h = x @ W ; el = (h*al).sum(-1) ; er = (h*ar).sum(-1) ----------------
// block 256 threads: c = t&127 (output column), g = t>>7 (node-group of 8). 16 nodes/block.
__global__ __launch_bounds__(256) void k_gemm_h(
    const float* __restrict__ x, const float* __restrict__ W,
    const float* __restrict__ al, const float* __restrict__ ar,
    float* __restrict__ h, float* __restrict__ el, float* __restrict__ er, int N)
{
  __shared__ __align__(16) float xs[16][DD];
  __shared__ float redl[16][2], redr[16][2];
  const int t = threadIdx.x;
  const int c = t & 127, g = t >> 7;
  const int n0 = blockIdx.x * 16;

  for (int i = t; i < 16 * 32; i += 256) {
    int row = i >> 5, col4 = i & 31;
    int n = n0 + row;
    float4 v = make_float4(0.f, 0.f, 0.f, 0.f);
    if (n < N) v = *(const float4*)(x + (size_t)n * DD + col4 * 4);
    *(float4*)&xs[row][col4 * 4] = v;
  }
  __syncthreads();

  float acc[8];
#pragma unroll
  for (int j = 0; j < 8; j++) acc[j] = 0.f;
  const float* Wc = W + c;
  for (int k = 0; k < DD; k += 4) {
    float w0 = Wc[(size_t)k * DD];
    float w1 = Wc[(size_t)(k + 1) * DD];
    float w2 = Wc[(size_t)(k + 2) * DD];
    float w3 = Wc[(size_t)(k + 3) * DD];
#pragma unroll
    for (int j = 0; j < 8; j++) {
      float4 xv = *(const float4*)&xs[g * 8 + j][k];
      acc[j] = fmaf(xv.x, w0, fmaf(xv.y, w1, fmaf(xv.z, w2, fmaf(xv.w, w3, acc[j]))));
    }
  }

  const float alc = al[c], arc = ar[c];
#pragma unroll
  for (int j = 0; j < 8; j++) {
    int n = n0 + g * 8 + j;
    if (n < N) h[(size_t)n * DD + c] = acc[j];
    float vl = acc[j] * alc, vr = acc[j] * arc;
#pragma unroll
    for (int o = 32; o; o >>= 1) { vl += __shfl_xor(vl, o); vr += __shfl_xor(vr, o); }
    if ((t & 63) == 0) { int w = t >> 6; redl[g * 8 + j][w & 1] = vl; redr[g * 8 + j][w & 1] = vr; }
  }
  __syncthreads();
  if (t < 16) {
    int n = n0 + t;
    if (n < N) { el[n] = redl[t][0] + redl[t][1]; er[n] = redr[t][0] + redr[t][1]; }
  }
}

// ---------------- CSR build: histogram of dst ----------------
__global__ void k_hist(const int* __restrict__ dst, int* __restrict__ cnt, int E) {
  int i = blockIdx.x * 256 + threadIdx.x;
  if (i < E) atomicAdd(cnt + dst[i], 1);
}

// ---------------- single-block exclusive scan over N counts -> base ----------------
__global__ __launch_bounds__(1024) void k_scan(const int* __restrict__ cnt,
                                               int* __restrict__ base, int N)
{
  __shared__ int sums[1024];
  const int t = threadIdx.x;
  const int chunk = (N + 1023) / 1024;
  const int b = t * chunk;
  const int e = min(b + chunk, N);
  int s = 0;
  for (int i = b; i < e; i++) s += cnt[i];
  sums[t] = s;
  __syncthreads();
  for (int o = 1; o < 1024; o <<= 1) {
    int u = (t >= o) ? sums[t - o] : 0;
    __syncthreads();
    sums[t] += u;
    __syncthreads();
  }
  int run = sums[t] - s;  // exclusive prefix for this chunk
  for (int i = b; i < e; i++) { base[i] = run; run += cnt[i]; }
}

// ---------------- scatter edges into CSR order; precompute e = lrelu(el[src]+er[dst]) ----------------
__global__ void k_scatter(const int* __restrict__ src, const int* __restrict__ dst,
    const float* __restrict__ ew, const float* __restrict__ el, const float* __restrict__ er,
    const int* __restrict__ base, int* __restrict__ cnt2,
    int* __restrict__ srcs, float* __restrict__ ewws, float* __restrict__ es, int E)
{
  int i = blockIdx.x * 256 + threadIdx.x;
  if (i >= E) return;
  int d = dst[i], s = src[i];
  int pos = base[d] + atomicAdd(cnt2 + d, 1);
  srcs[pos] = s;
  ewws[pos] = ew[i];
  es[pos] = lrelu(el[s] + er[d], 0.2f);
}

// ---------------- per-node fused softmax + aggregate + relation-accumulate ----------------
// one 64-lane wave per dst node; lane owns channels [2*lane, 2*lane+1].
__global__ __launch_bounds__(256) void k_node_agg(
    const int* __restrict__ base, const int* __restrict__ cnt,
    const int* __restrict__ srcs, const float* __restrict__ ewws, const float* __restrict__ es,
    const float* __restrict__ h, const float* __restrict__ gb,
    float* __restrict__ sacc, float* __restrict__ qacc, int N, int first)
{
  const int wid = (int)(((long long)blockIdx.x * 256 + threadIdx.x) >> 6);  // node id
  const int lane = threadIdx.x & 63;
  if (wid >= N) return;
  const int beg = base[wid];
  const int deg = cnt[wid];

  // pass 1: segment max
  float m = -1e30f;
  for (int j = lane; j < deg; j += 64) m = fmaxf(m, es[beg + j]);
#pragma unroll
  for (int o = 32; o; o >>= 1) m = fmaxf(m, __shfl_xor(m, o));

  // pass 2: softmax numerators + weighted gather-accumulate
  float2 acc = make_float2(0.f, 0.f);
  float ssum = 0.f;
  for (int c0 = 0; c0 < deg; c0 += 64) {
    const int k = min(64, deg - c0);
    float a = 0.f, cw = 0.f;
    int sv = 0;
    if (lane < k) {
      int j = beg + c0 + lane;
      a = __expf(es[j] - m);
      sv = srcs[j];
      cw = a * ewws[j];
    }
    ssum += a;
    for (int j = 0; j < k; j++) {
      float cj = __shfl(cw, j);
      int sj = __shfl(sv, j);
      const float2 hv = *(const float2*)(h + (size_t)sj * DD + lane * 2);
      acc.x = fmaf(cj, hv.x, acc.x);
      acc.y = fmaf(cj, hv.y, acc.y);
    }
  }
#pragma unroll
  for (int o = 32; o; o >>= 1) ssum += __shfl_xor(ssum, o);

  const float inv = (deg > 0) ? 1.f / ssum : 0.f;
  const float2 bb = *(const float2*)(gb + lane * 2);
  const float fx = acc.x * inv + bb.x;
  const float fy = acc.y * inv + bb.y;

  float2* sp = (float2*)sacc + (size_t)wid * 64 + lane;
  float2* qp = (float2*)qacc + (size_t)wid * 64 + lane;
  if (first) {
    *sp = make_float2(fx, fy);
    *qp = make_float2(fx * fx, fy * fy);
  } else {
    float2 s = *sp, q = *qp;
    s.x += fx; s.y += fy;
    q.x += fx * fx; q.y += fy * fy;
    *sp = s; *qp = q;
  }
}

// ---------------- transpose 128x128 weight ----------------
__global__ void k_transpose(const float* __restrict__ w, float* __restrict__ wt) {
  int i = blockIdx.x * 256 + threadIdx.x;  // 16384 total
  int c = i >> 7, k = i & 127;
  wt[k * DD + c] = w[i];
}

// ---------------- combine: dfm/s matvecs + leaky + residual + LayerNorm ----------------
__global__ __launch_bounds__(128) void k_combine(
    const float* __restrict__ sacc, const float* __restrict__ qacc,
    const float* __restrict__ x,
    const float* __restrict__ biT, const float* __restrict__ siT,
    const float* __restrict__ bi_b, const float* __restrict__ si_b,
    const float* __restrict__ res_w, const float* __restrict__ ln_g,
    const float* __restrict__ ln_b,
    float* __restrict__ out, int N)
{
  __shared__ __align__(16) float st[DD][8], dt[DD][8];
  __shared__ float redm[8][2], redq[8][2];
  const int t = threadIdx.x;
  const int n0 = blockIdx.x * 8;

  for (int it = 0; it < 8; ++it) {
    int n = n0 + it;
    float s = 0.f, q = 0.f;
    if (n < N) { s = sacc[(size_t)n * DD + t]; q = qacc[(size_t)n * DD + t]; }
    st[t][it] = s;
    dt[t][it] = 0.5f * (s * s - q);
  }
  __syncthreads();

  float accB[8], accS[8];
#pragma unroll
  for (int j = 0; j < 8; j++) { accB[j] = 0.f; accS[j] = 0.f; }
  const float* bT = biT + t;
  const float* sT = siT + t;
  for (int k = 0; k < DD; k++) {
    float wb = bT[(size_t)k * DD];
    float ws = sT[(size_t)k * DD];
    float dv[8], sv[8];
    *(float4*)&dv[0] = *(const float4*)&dt[k][0];
    *(float4*)&dv[4] = *(const float4*)&dt[k][4];
    *(float4*)&sv[0] = *(const float4*)&st[k][0];
    *(float4*)&sv[4] = *(const float4*)&st[k][4];
#pragma unroll
    for (int j = 0; j < 8; j++) {
      accB[j] = fmaf(dv[j], wb, accB[j]);
      accS[j] = fmaf(sv[j], ws, accS[j]);
    }
  }

  const float sigw = 1.f / (1.f + __expf(-res_w[0]));
  const float bib = bi_b[t], sib = si_b[t], g = ln_g[t], bb = ln_b[t];
  float v[8];
#pragma unroll
  for (int j = 0; j < 8; j++) {
    int n = n0 + j;
    float xv = (n < N) ? x[(size_t)n * DD + t] : 0.f;
    float val = lrelu(accB[j] + bib, 0.01f) + lrelu(accS[j] + sib, 0.01f) + xv * sigw;
    v[j] = val;
    float sv = val, sq = val * val;
#pragma unroll
    for (int o = 32; o; o >>= 1) { sv += __shfl_xor(sv, o); sq += __shfl_xor(sq, o); }
    if ((t & 63) == 0) { redm[j][t >> 6] = sv; redq[j][t >> 6] = sq; }
  }
  __syncthreads();
#pragma unroll
  for (int j = 0; j < 8; j++) {
    int n = n0 + j;
    if (n >= N) continue;
    float mu = (redm[j][0] + redm[j][1]) * (1.f / DD);
    float ex2 = (redq[j][0] + redq[j][1]) * (1.f / DD);
    float var = ex2 - mu * mu;
    out[(size_t)n * DD + t] = (v[j] - mu) * rsqrtf(var + 1e-5f) * g + bb;
  }
}

extern "C" void kernel_launch(void* const* d_in, const int* in_sizes, int n_in,
                              void* d_out, int out_size, void* d_ws, size_t ws_size,
                              hipStream_t stream)
{
  const float* x    = (const float*)d_in[0];
  const int*   esrc = (const int*)d_in[1];
  const int*   edst = (const int*)d_in[2];
  const float* ew   = (const float*)d_in[3];
  const float* W    = (const float*)d_in[4];
  const float* al   = (const float*)d_in[5];
  const float* ar   = (const float*)d_in[6];
  const float* gb   = (const float*)d_in[7];
  const float* bi_w = (const float*)d_in[8];
  const float* bi_b = (const float*)d_in[9];
  const float* si_w = (const float*)d_in[10];
  const float* si_b = (const float*)d_in[11];
  const float* res_w= (const float*)d_in[12];
  const float* ln_g = (const float*)d_in[13];
  const float* ln_b = (const float*)d_in[14];

  const int N = in_sizes[0] / DD;
  const int R = 3;
  const int E = in_sizes[1] / R;
  const size_t ND = (size_t)N * DD;

  char* p = (char*)d_ws;
  float* h     = (float*)p; p += ND * 4;
  float* sacc  = (float*)p; p += ND * 4;
  float* qacc  = (float*)p; p += ND * 4;
  float* el    = (float*)p; p += (size_t)N * 4;
  float* er    = (float*)p; p += (size_t)N * 4;
  int*   cnt   = (int*)p;   p += (size_t)N * 4;   // cnt and cnt2 contiguous: one memset
  int*   cnt2  = (int*)p;   p += (size_t)N * 4;
  int*   base  = (int*)p;   p += (size_t)N * 4;
  int*   srcs  = (int*)p;   p += (size_t)E * 4;
  float* ewws  = (float*)p; p += (size_t)E * 4;
  float* es    = (float*)p; p += (size_t)E * 4;
  float* biT   = (float*)p; p += (size_t)DD * DD * 4;
  float* siT   = (float*)p; p += (size_t)DD * DD * 4;

  k_transpose<<<64, 256, 0, stream>>>(bi_w, biT);
  k_transpose<<<64, 256, 0, stream>>>(si_w, siT);

  const int egrid = (E + 255) / 256;
  for (int r = 0; r < R; r++) {
    const int* src_r = esrc + (size_t)r * E;
    const int* dst_r = edst + (size_t)r * E;
    const float* ew_r = ew + (size_t)r * E;

    k_gemm_h<<<(N + 15) / 16, 256, 0, stream>>>(
        x, W + (size_t)r * DD * DD, al + r * DD, ar + r * DD, h, el, er, N);

    hipMemsetAsync(cnt, 0, (size_t)2 * N * 4, stream);  // cnt + cnt2
    k_hist<<<egrid, 256, 0, stream>>>(dst_r, cnt, E);
    k_scan<<<1, 1024, 0, stream>>>(cnt, base, N);
    k_scatter<<<egrid, 256, 0, stream>>>(src_r, dst_r, ew_r, el, er,
                                         base, cnt2, srcs, ewws, es, E);
    k_node_agg<<<(N + 3) / 4, 256, 0, stream>>>(
        base, cnt, srcs, ewws, es, h, gb + r * DD, sacc, qacc, N, r == 0);
  }
  k_combine<<<(N + 7) / 8, 128, 0, stream>>>(
      sacc, qacc, x, biT, siT, bi_b, si_b, res_w, ln_g, ln_b, (float*)d_out, N);
}

// Round 3
// 853.527 us; speedup vs baseline: 4.4365x; 1.5977x over previous
//
#include <hip/hip_runtime.h>
#include <hip/hip_bf16.h>

#define DD 128
typedef unsigned int u32;

__device__ __forceinline__ float lrelu(float v, float s) { return v >= 0.f ? v : s * v; }

// ---------------- fused 3-relation: h_r = x @ W_r (bf16 out); el_r, er_r ----------------
// block 256: c = t&127 (output column), g = t>>7 (node-group of 8). 16 nodes/block.
__global__ __launch_bounds__(256) void k_gemm_all(
    const float* __restrict__ x, const float* __restrict__ W,
    const float* __restrict__ al, const float* __restrict__ ar,
    __hip_bfloat16* __restrict__ hb, float* __restrict__ el, float* __restrict__ er, int N)
{
  __shared__ __align__(16) float xs[16][DD];
  __shared__ float redl[3][16][2], redr[3][16][2];
  const int t = threadIdx.x;
  const int c = t & 127, g = t >> 7;
  const int n0 = blockIdx.x * 16;

  for (int i = t; i < 16 * 32; i += 256) {
    int row = i >> 5, col4 = i & 31;
    int n = n0 + row;
    float4 v = make_float4(0.f, 0.f, 0.f, 0.f);
    if (n < N) v = *(const float4*)(x + (size_t)n * DD + col4 * 4);
    *(float4*)&xs[row][col4 * 4] = v;
  }
  __syncthreads();

  for (int r = 0; r < 3; r++) {
    float acc[8];
#pragma unroll
    for (int j = 0; j < 8; j++) acc[j] = 0.f;
    const float* Wc = W + (size_t)r * DD * DD + c;
    for (int k = 0; k < DD; k += 4) {
      float w0 = Wc[(size_t)k * DD];
      float w1 = Wc[(size_t)(k + 1) * DD];
      float w2 = Wc[(size_t)(k + 2) * DD];
      float w3 = Wc[(size_t)(k + 3) * DD];
#pragma unroll
      for (int j = 0; j < 8; j++) {
        float4 xv = *(const float4*)&xs[g * 8 + j][k];
        acc[j] = fmaf(xv.x, w0, fmaf(xv.y, w1, fmaf(xv.z, w2, fmaf(xv.w, w3, acc[j]))));
      }
    }
    const float alc = al[r * DD + c], arc = ar[r * DD + c];
#pragma unroll
    for (int j = 0; j < 8; j++) {
      int n = n0 + g * 8 + j;
      if (n < N) hb[((size_t)r * N + n) * DD + c] = __float2bfloat16(acc[j]);
      float vl = acc[j] * alc, vr = acc[j] * arc;
#pragma unroll
      for (int o = 32; o; o >>= 1) { vl += __shfl_xor(vl, o); vr += __shfl_xor(vr, o); }
      if ((t & 63) == 0) {
        int w = (t >> 6) & 1;
        redl[r][g * 8 + j][w] = vl; redr[r][g * 8 + j][w] = vr;
      }
    }
  }
  __syncthreads();
  if (t < 48) {
    int r = t >> 4, nl = t & 15;
    int n = n0 + nl;
    if (n < N) {
      el[(size_t)r * N + n] = redl[r][nl][0] + redl[r][nl][1];
      er[(size_t)r * N + n] = redr[r][nl][0] + redr[r][nl][1];
    }
  }
}

// ---------------- CSR build: histogram of dst, all 3 relations (grid.y = r) ----------------
__global__ void k_hist3(const int* __restrict__ dst, int* __restrict__ cnt, int N, int E) {
  int i = blockIdx.x * 256 + threadIdx.x;
  int r = blockIdx.y;
  if (i < E) atomicAdd(cnt + (size_t)r * N + dst[(size_t)r * E + i], 1);
}

// ---------------- hierarchical scan over M = 3N counts ----------------
// each block owns 2048 counts (8 per thread)
__global__ __launch_bounds__(256) void k_scan_bsum(const int* __restrict__ cnt,
                                                   int* __restrict__ bsum, int M)
{
  __shared__ int red[256];
  const int t = threadIdx.x;
  const int g0 = blockIdx.x * 2048 + t * 8;
  int s = 0;
#pragma unroll
  for (int j = 0; j < 8; j++) { int i = g0 + j; if (i < M) s += cnt[i]; }
  red[t] = s;
  __syncthreads();
  for (int o = 128; o; o >>= 1) {
    if (t < o) red[t] += red[t + o];
    __syncthreads();
  }
  if (t == 0) bsum[blockIdx.x] = red[0];
}

__global__ __launch_bounds__(256) void k_scan_btop(const int* __restrict__ bsum,
                                                   int* __restrict__ bpre, int NB)
{
  __shared__ int sums[256];
  const int t = threadIdx.x;
  int v = (t < NB) ? bsum[t] : 0;
  sums[t] = v;
  __syncthreads();
  for (int o = 1; o < 256; o <<= 1) {
    int u = (t >= o) ? sums[t - o] : 0;
    __syncthreads();
    sums[t] += u;
    __syncthreads();
  }
  if (t < NB) bpre[t] = sums[t] - v;  // exclusive
}

__global__ __launch_bounds__(256) void k_scan_base(const int* __restrict__ cnt,
    const int* __restrict__ bpre, int* __restrict__ base, int M)
{
  __shared__ int sums[256];
  const int t = threadIdx.x;
  const int g0 = blockIdx.x * 2048 + t * 8;
  int c[8];
  int ts = 0;
#pragma unroll
  for (int j = 0; j < 8; j++) { int i = g0 + j; c[j] = (i < M) ? cnt[i] : 0; ts += c[j]; }
  sums[t] = ts;
  __syncthreads();
  for (int o = 1; o < 256; o <<= 1) {
    int u = (t >= o) ? sums[t - o] : 0;
    __syncthreads();
    sums[t] += u;
    __syncthreads();
  }
  int run = bpre[blockIdx.x] + sums[t] - ts;
#pragma unroll
  for (int j = 0; j < 8; j++) {
    int i = g0 + j;
    if (i < M) base[i] = run;
    run += c[j];
  }
}

// ---------------- scatter edges into CSR order (grid.y = r) ----------------
__global__ void k_scatter3(const int* __restrict__ src, const int* __restrict__ dst,
    const float* __restrict__ ew, const float* __restrict__ el, const float* __restrict__ er,
    const int* __restrict__ base, int* __restrict__ cnt2,
    int* __restrict__ srcs, float* __restrict__ ewws, float* __restrict__ es, int N, int E)
{
  int i = blockIdx.x * 256 + threadIdx.x;
  if (i >= E) return;
  int r = blockIdx.y;
  size_t ei = (size_t)r * E + i;
  int d = dst[ei], s = src[ei];
  size_t node = (size_t)r * N + d;
  int pos = base[node] + atomicAdd(cnt2 + node, 1);
  srcs[pos] = s;
  ewws[pos] = ew[ei];
  es[pos] = lrelu(el[(size_t)r * N + s] + er[node], 0.2f);
}

// ---------------- fused per-node softmax+aggregate over ALL 3 relations ----------------
// one 64-lane wave per node; lane owns channels [2*lane, 2*lane+1]; h is bf16.
__global__ __launch_bounds__(256) void k_node_agg3(
    const int* __restrict__ base, const int* __restrict__ cnt,
    const int* __restrict__ srcs, const float* __restrict__ ewws, const float* __restrict__ es,
    const __hip_bfloat16* __restrict__ hb, const float* __restrict__ gb,
    float* __restrict__ sacc, float* __restrict__ qacc, int N)
{
  const int wid = (int)(((long long)blockIdx.x * 256 + threadIdx.x) >> 6);
  const int lane = threadIdx.x & 63;
  if (wid >= N) return;

  float sx = 0.f, sy = 0.f, qx = 0.f, qy = 0.f;

  for (int r = 0; r < 3; r++) {
    const size_t node = (size_t)r * N + wid;
    const int beg = base[node];
    const int deg = cnt[node];
    const size_t hbase = (size_t)r * N * DD + lane * 2;

    float m = -1e30f;
    for (int j = lane; j < deg; j += 64) m = fmaxf(m, es[beg + j]);
#pragma unroll
    for (int o = 32; o; o >>= 1) m = fmaxf(m, __shfl_xor(m, o));

    float ax = 0.f, ay = 0.f, ssum = 0.f;
    for (int c0 = 0; c0 < deg; c0 += 64) {
      const int k = min(64, deg - c0);
      float a = 0.f, cw = 0.f;
      int sv = 0;
      if (lane < k) {
        int j = beg + c0 + lane;
        a = __expf(es[j] - m);
        sv = srcs[j];
        cw = a * ewws[j];
      }
      ssum += a;
      for (int j = 0; j < k; j++) {
        float cj = __shfl(cw, j);
        int sj = __shfl(sv, j);
        u32 u = *(const u32*)(hb + hbase + (size_t)sj * DD);
        float lo = __uint_as_float(u << 16);
        float hi = __uint_as_float(u & 0xFFFF0000u);
        ax = fmaf(cj, lo, ax);
        ay = fmaf(cj, hi, ay);
      }
    }
#pragma unroll
    for (int o = 32; o; o >>= 1) ssum += __shfl_xor(ssum, o);

    const float inv = (deg > 0) ? 1.f / ssum : 0.f;
    const float fx = ax * inv + gb[r * DD + lane * 2];
    const float fy = ay * inv + gb[r * DD + lane * 2 + 1];
    sx += fx; sy += fy;
    qx += fx * fx; qy += fy * fy;
  }

  ((float2*)sacc)[(size_t)wid * 64 + lane] = make_float2(sx, sy);
  ((float2*)qacc)[(size_t)wid * 64 + lane] = make_float2(qx, qy);
}

// ---------------- transpose both 128x128 weights ----------------
__global__ void k_transpose2(const float* __restrict__ bw, const float* __restrict__ sw,
                             float* __restrict__ bt, float* __restrict__ st) {
  int i = blockIdx.x * 256 + threadIdx.x;  // 32768
  int m = i >> 14, j = i & 16383;
  int c = j >> 7, k = j & 127;
  if (m) st[k * DD + c] = sw[j];
  else   bt[k * DD + c] = bw[j];
}

// ---------------- combine: dfm/s matvecs + leaky + residual + LayerNorm ----------------
// block 256: c = t&127 (col), g = t>>7. 16 nodes/block. Conflict-free LDS transpose.
__global__ __launch_bounds__(256) void k_combine(
    const float* __restrict__ sacc, const float* __restrict__ qacc,
    const float* __restrict__ x,
    const float* __restrict__ biT, const float* __restrict__ siT,
    const float* __restrict__ bi_b, const float* __restrict__ si_b,
    const float* __restrict__ res_w, const float* __restrict__ ln_g,
    const float* __restrict__ ln_b,
    float* __restrict__ out, int N)
{
  __shared__ __align__(16) float st[DD][16], dt[DD][16];
  __shared__ float redm[16][2], redq[16][2];
  const int t = threadIdx.x;
  const int c = t & 127, g = t >> 7;
  const int n0 = blockIdx.x * 16;

  float sld[8], dld[8];
#pragma unroll
  for (int it = 0; it < 8; it++) {
    int n = n0 + g * 8 + it;
    float s = 0.f, q = 0.f;
    if (n < N) { s = sacc[(size_t)n * DD + c]; q = qacc[(size_t)n * DD + c]; }
    sld[it] = s;
    dld[it] = 0.5f * (s * s - q);
  }
  *(float4*)&st[c][g * 8]     = *(float4*)&sld[0];
  *(float4*)&st[c][g * 8 + 4] = *(float4*)&sld[4];
  *(float4*)&dt[c][g * 8]     = *(float4*)&dld[0];
  *(float4*)&dt[c][g * 8 + 4] = *(float4*)&dld[4];
  __syncthreads();

  float accB[8], accS[8];
#pragma unroll
  for (int j = 0; j < 8; j++) { accB[j] = 0.f; accS[j] = 0.f; }
  const float* bT = biT + c;
  const float* sT = siT + c;
  for (int k = 0; k < DD; k++) {
    float wb = bT[(size_t)k * DD];
    float ws = sT[(size_t)k * DD];
    float4 d0 = *(const float4*)&dt[k][g * 8];
    float4 d1 = *(const float4*)&dt[k][g * 8 + 4];
    float4 s0 = *(const float4*)&st[k][g * 8];
    float4 s1 = *(const float4*)&st[k][g * 8 + 4];
    accB[0] = fmaf(d0.x, wb, accB[0]); accS[0] = fmaf(s0.x, ws, accS[0]);
    accB[1] = fmaf(d0.y, wb, accB[1]); accS[1] = fmaf(s0.y, ws, accS[1]);
    accB[2] = fmaf(d0.z, wb, accB[2]); accS[2] = fmaf(s0.z, ws, accS[2]);
    accB[3] = fmaf(d0.w, wb, accB[3]); accS[3] = fmaf(s0.w, ws, accS[3]);
    accB[4] = fmaf(d1.x, wb, accB[4]); accS[4] = fmaf(s1.x, ws, accS[4]);
    accB[5] = fmaf(d1.y, wb, accB[5]); accS[5] = fmaf(s1.y, ws, accS[5]);
    accB[6] = fmaf(d1.z, wb, accB[6]); accS[6] = fmaf(s1.z, ws, accS[6]);
    accB[7] = fmaf(d1.w, wb, accB[7]); accS[7] = fmaf(s1.w, ws, accS[7]);
  }

  const float sigw = 1.f / (1.f + __expf(-res_w[0]));
  const float bib = bi_b[c], sib = si_b[c], gg = ln_g[c], bb = ln_b[c];
  float v[8];
#pragma unroll
  for (int j = 0; j < 8; j++) {
    int n = n0 + g * 8 + j;
    float xv = (n < N) ? x[(size_t)n * DD + c] : 0.f;
    float val = lrelu(accB[j] + bib, 0.01f) + lrelu(accS[j] + sib, 0.01f) + xv * sigw;
    v[j] = val;
    float sv = val, sq = val * val;
#pragma unroll
    for (int o = 32; o; o >>= 1) { sv += __shfl_xor(sv, o); sq += __shfl_xor(sq, o); }
    if ((t & 63) == 0) { int w = (t >> 6) & 1; redm[g * 8 + j][w] = sv; redq[g * 8 + j][w] = sq; }
  }
  __syncthreads();
#pragma unroll
  for (int j = 0; j < 8; j++) {
    int n = n0 + g * 8 + j;
    if (n >= N) continue;
    float mu = (redm[g * 8 + j][0] + redm[g * 8 + j][1]) * (1.f / DD);
    float ex2 = (redq[g * 8 + j][0] + redq[g * 8 + j][1]) * (1.f / DD);
    float var = ex2 - mu * mu;
    out[(size_t)n * DD + c] = (v[j] - mu) * rsqrtf(var + 1e-5f) * gg + bb;
  }
}

extern "C" void kernel_launch(void* const* d_in, const int* in_sizes, int n_in,
                              void* d_out, int out_size, void* d_ws, size_t ws_size,
                              hipStream_t stream)
{
  const float* x    = (const float*)d_in[0];
  const int*   esrc = (const int*)d_in[1];
  const int*   edst = (const int*)d_in[2];
  const float* ew   = (const float*)d_in[3];
  const float* W    = (const float*)d_in[4];
  const float* al   = (const float*)d_in[5];
  const float* ar   = (const float*)d_in[6];
  const float* gb   = (const float*)d_in[7];
  const float* bi_w = (const float*)d_in[8];
  const float* bi_b = (const float*)d_in[9];
  const float* si_w = (const float*)d_in[10];
  const float* si_b = (const float*)d_in[11];
  const float* res_w= (const float*)d_in[12];
  const float* ln_g = (const float*)d_in[13];
  const float* ln_b = (const float*)d_in[14];

  const int N = in_sizes[0] / DD;
  const int R = 3;
  const int E = in_sizes[1] / R;
  const size_t ND = (size_t)N * DD;
  const int M = R * N;                      // total CSR segments
  const int NB = (M + 2047) / 2048;         // scan blocks (147 for N=100k; <=256 required)

  char* p = (char*)d_ws;
  __hip_bfloat16* hb = (__hip_bfloat16*)p; p += (size_t)R * ND * 2;
  float* sacc  = (float*)p; p += ND * 4;
  float* qacc  = (float*)p; p += ND * 4;
  float* el    = (float*)p; p += (size_t)M * 4;
  float* er    = (float*)p; p += (size_t)M * 4;
  int*   cnt   = (int*)p;   p += (size_t)M * 4;   // cnt+cnt2 contiguous for one memset
  int*   cnt2  = (int*)p;   p += (size_t)M * 4;
  int*   base  = (int*)p;   p += (size_t)M * 4;
  int*   bsum  = (int*)p;   p += 1024;
  int*   bpre  = (int*)p;   p += 1024;
  int*   srcs  = (int*)p;   p += (size_t)R * E * 4;
  float* ewws  = (float*)p; p += (size_t)R * E * 4;
  float* es    = (float*)p; p += (size_t)R * E * 4;
  float* biT   = (float*)p; p += (size_t)DD * DD * 4;
  float* siT   = (float*)p; p += (size_t)DD * DD * 4;

  const int egrid = (E + 255) / 256;

  k_transpose2<<<128, 256, 0, stream>>>(bi_w, si_w, biT, siT);
  k_gemm_all<<<(N + 15) / 16, 256, 0, stream>>>(x, W, al, ar, hb, el, er, N);

  hipMemsetAsync(cnt, 0, (size_t)2 * M * 4, stream);
  k_hist3<<<dim3(egrid, 3), 256, 0, stream>>>(edst, cnt, N, E);
  k_scan_bsum<<<NB, 256, 0, stream>>>(cnt, bsum, M);
  k_scan_btop<<<1, 256, 0, stream>>>(bsum, bpre, NB);
  k_scan_base<<<NB, 256, 0, stream>>>(cnt, bpre, base, M);
  k_scatter3<<<dim3(egrid, 3), 256, 0, stream>>>(esrc, edst, ew, el, er,
                                                 base, cnt2, srcs, ewws, es, N, E);
  k_node_agg3<<<(N + 3) / 4, 256, 0, stream>>>(base, cnt, srcs, ewws, es, hb, gb,
                                               sacc, qacc, N);
  k_combine<<<(N + 15) / 16, 256, 0, stream>>>(
      sacc, qacc, x, biT, siT, bi_b, si_b, res_w, ln_g, ln_b, (float*)d_out, N);
}

// Round 4
// 630.361 us; speedup vs baseline: 6.0072x; 1.3540x over previous
//
#include <hip/hip_runtime.h>

#define DD 128
typedef unsigned int u32;
typedef __attribute__((ext_vector_type(8))) short bf16x8;
typedef __attribute__((ext_vector_type(4))) float f32x4;

__device__ __forceinline__ float lrelu(float v, float s) { return v >= 0.f ? v : s * v; }
__device__ __forceinline__ ushort f2bf(float f) {
  union { float f; u32 u; } v; v.f = f;
  u32 u = v.u;
  return (ushort)((u + 0x7FFFu + ((u >> 16) & 1u)) >> 16);  // RNE
}
__device__ __forceinline__ float bf2f(ushort s) { return __uint_as_float(((u32)s) << 16); }

// ---------------- prep: x (f32) -> bf16 MFMA B-fragment layout ----------------
// xb[(n>>4)*4 + kstep][lane][8]: lane l holds x[n0+(l&15)][kstep*32+(l>>4)*8 + j]
__global__ __launch_bounds__(256) void k_prep_x(
    const float* __restrict__ x, short* __restrict__ xb, int N, int Np)
{
  int t = blockIdx.x * 256 + threadIdx.x;  // t < Np*16
  int lane = t & 63;
  int n = ((t >> 8) << 4) | (lane & 15);
  int k = ((t >> 6) & 3) * 32 + (lane >> 4) * 8;
  float xv[8];
  if (n < N) {
    float4 a = *(const float4*)(x + (size_t)n * DD + k);
    float4 b = *(const float4*)(x + (size_t)n * DD + k + 4);
    xv[0] = a.x; xv[1] = a.y; xv[2] = a.z; xv[3] = a.w;
    xv[4] = b.x; xv[5] = b.y; xv[6] = b.z; xv[7] = b.w;
  } else {
#pragma unroll
    for (int j = 0; j < 8; j++) xv[j] = 0.f;
  }
  uint4 st;
  st.x = (u32)f2bf(xv[0]) | ((u32)f2bf(xv[1]) << 16);
  st.y = (u32)f2bf(xv[2]) | ((u32)f2bf(xv[3]) << 16);
  st.z = (u32)f2bf(xv[4]) | ((u32)f2bf(xv[5]) << 16);
  st.w = (u32)f2bf(xv[6]) | ((u32)f2bf(xv[7]) << 16);
  *(uint4*)(xb + (size_t)t * 8) = st;
}

// ---------------- prep: W^T -> bf16 MFMA A-fragment layout ----------------
// WA[r][cf][kstep][lane][8]: lane l holds W[k][c] with c=cf*16+(l&15), k=kstep*32+(l>>4)*8+j
__global__ __launch_bounds__(256) void k_prep_w(const float* __restrict__ W,
                                                short* __restrict__ WA)
{
  int t = blockIdx.x * 256 + threadIdx.x;  // 6144
  int lane = t & 63, ks = (t >> 6) & 3, cf = (t >> 8) & 7, r = t >> 11;
  int c = cf * 16 + (lane & 15);
  int kb = ks * 32 + (lane >> 4) * 8;
  const float* Wr = W + (size_t)r * DD * DD;
  ushort o[8];
#pragma unroll
  for (int j = 0; j < 8; j++) o[j] = f2bf(Wr[(size_t)(kb + j) * DD + c]);
  uint4 st;
  st.x = (u32)o[0] | ((u32)o[1] << 16);
  st.y = (u32)o[2] | ((u32)o[3] << 16);
  st.z = (u32)o[4] | ((u32)o[5] << 16);
  st.w = (u32)o[6] | ((u32)o[7] << 16);
  *(uint4*)(WA + (size_t)t * 8) = st;
}

// ---------------- prep: wl = W @ attn_l, wr = W @ attn_r (per relation) ----------------
__global__ void k_prep_av(const float* __restrict__ W, const float* __restrict__ al,
                          const float* __restrict__ ar, float* __restrict__ wl,
                          float* __restrict__ wr)
{
  int t = blockIdx.x * 192 + threadIdx.x;  // 384
  if (t >= 384) return;
  int r = t >> 7, k = t & 127;
  const float* Wrow = W + (size_t)r * DD * DD + (size_t)k * DD;
  const float* alr = al + r * DD;
  const float* arr = ar + r * DD;
  float pl = 0.f, pr = 0.f;
  for (int c = 0; c < DD; c++) { float w = Wrow[c]; pl = fmaf(w, alr[c], pl); pr = fmaf(w, arr[c], pr); }
  wl[t] = pl; wr[t] = pr;
}

// ---------------- MFMA: h = x@W (all 3 relations), el/er epilogue ----------------
// block 256 = 4 waves; wave: 32 nodes x 128 channels. D = A(W^T) * B(x):
// D[c][n]: lane holds node=(l&15), channels cf*16+(l>>4)*4+reg  -> contiguous 8B stores.
__global__ __launch_bounds__(256) void k_mfma_h(
    const short* __restrict__ xb, const short* __restrict__ WA,
    const float* __restrict__ wl, const float* __restrict__ wr,
    short* __restrict__ h, float* __restrict__ el, float* __restrict__ er,
    int N, int Np)
{
  const int lane = threadIdx.x & 63;
  const int w = threadIdx.x >> 6;
  const int n0 = blockIdx.x * 128 + w * 32;
  const int rb = n0 >> 4;

  bf16x8 xf[2][4];
#pragma unroll
  for (int nf = 0; nf < 2; nf++)
#pragma unroll
    for (int ks = 0; ks < 4; ks++)
      xf[nf][ks] = *(const bf16x8*)(xb + (((size_t)(rb + nf) * 4 + ks) * 64 + lane) * 8);

  for (int r = 0; r < 3; r++) {
    f32x4 acc[2][8];
#pragma unroll
    for (int nf = 0; nf < 2; nf++)
#pragma unroll
      for (int cf = 0; cf < 8; cf++) acc[nf][cf] = (f32x4){0.f, 0.f, 0.f, 0.f};

#pragma unroll
    for (int ks = 0; ks < 4; ks++) {
      bf16x8 af[8];
#pragma unroll
      for (int cf = 0; cf < 8; cf++)
        af[cf] = *(const bf16x8*)(WA + ((((size_t)r * 8 + cf) * 4 + ks) * 64 + lane) * 8);
#pragma unroll
      for (int nf = 0; nf < 2; nf++)
#pragma unroll
        for (int cf = 0; cf < 8; cf++)
          acc[nf][cf] = __builtin_amdgcn_mfma_f32_16x16x32_bf16(af[cf], xf[nf][ks],
                                                                acc[nf][cf], 0, 0, 0);
    }

    // store h (bf16, 8B per lane per frag, channels contiguous)
#pragma unroll
    for (int nf = 0; nf < 2; nf++) {
      int node = n0 + nf * 16 + (lane & 15);
      if (node < N) {
        size_t rowoff = ((size_t)r * Np + node) * DD + (lane >> 4) * 4;
#pragma unroll
        for (int cf = 0; cf < 8; cf++) {
          uint2 uu;
          uu.x = (u32)f2bf(acc[nf][cf][0]) | ((u32)f2bf(acc[nf][cf][1]) << 16);
          uu.y = (u32)f2bf(acc[nf][cf][2]) | ((u32)f2bf(acc[nf][cf][3]) << 16);
          *(uint2*)(h + rowoff + cf * 16) = uu;
        }
      }
    }

    // el/er: dot(x_row, wl/wr) from register-resident x frags
#pragma unroll
    for (int nf = 0; nf < 2; nf++) {
      float pl = 0.f, pr = 0.f;
#pragma unroll
      for (int ks = 0; ks < 4; ks++) {
        const float* wlp = wl + r * DD + ks * 32 + (lane >> 4) * 8;
        const float* wrp = wr + r * DD + ks * 32 + (lane >> 4) * 8;
#pragma unroll
        for (int j = 0; j < 8; j++) {
          float xv = bf2f((ushort)xf[nf][ks][j]);
          pl = fmaf(xv, wlp[j], pl);
          pr = fmaf(xv, wrp[j], pr);
        }
      }
      pl += __shfl_xor(pl, 16); pl += __shfl_xor(pl, 32);
      pr += __shfl_xor(pr, 16); pr += __shfl_xor(pr, 32);
      int node = n0 + nf * 16 + lane;
      if (lane < 16 && node < N) {
        el[(size_t)r * N + node] = pl;
        er[(size_t)r * N + node] = pr;
      }
    }
  }
}

// ---------------- CSR build: histogram of dst (grid.y = r) ----------------
__global__ void k_hist3(const int* __restrict__ dst, int* __restrict__ cnt, int N, int E) {
  int i = blockIdx.x * 256 + threadIdx.x;
  int r = blockIdx.y;
  if (i < E) atomicAdd(cnt + (size_t)r * N + dst[(size_t)r * E + i], 1);
}

// ---------------- hierarchical scan: base[0..M] (inclusive of total at M) ----------------
__global__ __launch_bounds__(256) void k_scan_bsum(const int* __restrict__ cnt,
                                                   int* __restrict__ bsum, int M)
{
  __shared__ int red[256];
  const int t = threadIdx.x;
  const int g0 = blockIdx.x * 2048 + t * 8;
  int s = 0;
#pragma unroll
  for (int j = 0; j < 8; j++) { int i = g0 + j; if (i < M) s += cnt[i]; }
  red[t] = s;
  __syncthreads();
  for (int o = 128; o; o >>= 1) {
    if (t < o) red[t] += red[t + o];
    __syncthreads();
  }
  if (t == 0) bsum[blockIdx.x] = red[0];
}

__global__ __launch_bounds__(256) void k_scan_btop(const int* __restrict__ bsum,
                                                   int* __restrict__ bpre, int NB)
{
  __shared__ int sums[256];
  const int t = threadIdx.x;
  int v = (t < NB) ? bsum[t] : 0;
  sums[t] = v;
  __syncthreads();
  for (int o = 1; o < 256; o <<= 1) {
    int u = (t >= o) ? sums[t - o] : 0;
    __syncthreads();
    sums[t] += u;
    __syncthreads();
  }
  if (t < NB) bpre[t] = sums[t] - v;
}

__global__ __launch_bounds__(256) void k_scan_base(const int* __restrict__ cnt,
    const int* __restrict__ bpre, int* __restrict__ base, int M)
{
  __shared__ int sums[256];
  const int t = threadIdx.x;
  const int g0 = blockIdx.x * 2048 + t * 8;
  int c[8];
  int ts = 0;
#pragma unroll
  for (int j = 0; j < 8; j++) { int i = g0 + j; c[j] = (i < M) ? cnt[i] : 0; ts += c[j]; }
  sums[t] = ts;
  __syncthreads();
  for (int o = 1; o < 256; o <<= 1) {
    int u = (t >= o) ? sums[t - o] : 0;
    __syncthreads();
    sums[t] += u;
    __syncthreads();
  }
  int run = bpre[blockIdx.x] + sums[t] - ts;
#pragma unroll
  for (int j = 0; j < 8; j++) {
    int i = g0 + j;
    if (i <= M) base[i] = run;
    run += c[j];
  }
}

// ---------------- scatter: CSR edge-index permutation only (4B/edge) ----------------
__global__ void k_scatter3(const int* __restrict__ dst, const int* __restrict__ base,
                           int* __restrict__ cnt, int* __restrict__ eperm, int N, int E)
{
  int i = blockIdx.x * 256 + threadIdx.x;
  if (i >= E) return;
  int r = blockIdx.y;
  size_t node = (size_t)r * N + dst[(size_t)r * E + i];
  int pos = base[node] + (atomicSub(cnt + node, 1) - 1);
  eperm[pos] = i;
}

// ---------------- fused per-node softmax+aggregate, all 3 relations ----------------
// one wave per node; lane owns channels [4*(lane&31) .. +3]; 2 edges/iter via halves.
__global__ __launch_bounds__(256) void k_node_agg3(
    const int* __restrict__ base, const int* __restrict__ eperm,
    const int* __restrict__ esrc, const float* __restrict__ ew,
    const float* __restrict__ el, const float* __restrict__ er,
    const short* __restrict__ h, const float* __restrict__ gb,
    float* __restrict__ sacc, float* __restrict__ qacc, int N, int Np, int E)
{
  const int wid = (int)(((long long)blockIdx.x * 256 + threadIdx.x) >> 6);
  const int lane = threadIdx.x & 63;
  if (wid >= N) return;
  const int ql = lane & 31, half = lane >> 5;

  float s0 = 0, s1 = 0, s2 = 0, s3 = 0, q0 = 0, q1 = 0, q2 = 0, q3 = 0;

  for (int r = 0; r < 3; r++) {
    const int nid = r * N + wid;
    const int b0 = base[nid];
    const int deg = base[nid + 1] - b0;
    const int* esrc_r = esrc + (size_t)r * E;
    const float* ew_r = ew + (size_t)r * E;
    const float* el_r = el + (size_t)r * N;
    float a0 = 0, a1 = 0, a2 = 0, a3 = 0, ssum = 0.f;

    if (deg > 0) {
      const float ern = er[nid];
      if (deg <= 64) {
        float e = -1e30f, cw = 0.f; int sv = 0;
        if (lane < deg) {
          int eidx = eperm[b0 + lane];
          sv = esrc_r[eidx];
          e = lrelu(el_r[sv] + ern, 0.2f);
          cw = ew_r[eidx];
        }
        float m = e;
#pragma unroll
        for (int o = 32; o; o >>= 1) m = fmaxf(m, __shfl_xor(m, o));
        float a = 0.f;
        if (lane < deg) { a = __expf(e - m); cw *= a; }
        ssum = a;
#pragma unroll
        for (int o = 32; o; o >>= 1) ssum += __shfl_xor(ssum, o);
        const int iters = (deg + 1) >> 1;
        for (int jj = 0; jj < iters; jj++) {
          int j = jj * 2 + half;
          float cj = __shfl(cw, j);
          int sj = __shfl(sv, j);
          if (j < deg) {
            uint2 u = *(const uint2*)(h + ((size_t)r * Np + sj) * DD + ql * 4);
            a0 = fmaf(cj, __uint_as_float(u.x << 16), a0);
            a1 = fmaf(cj, __uint_as_float(u.x & 0xFFFF0000u), a1);
            a2 = fmaf(cj, __uint_as_float(u.y << 16), a2);
            a3 = fmaf(cj, __uint_as_float(u.y & 0xFFFF0000u), a3);
          }
        }
      } else {
        float m = -1e30f;
        for (int j2 = lane; j2 < deg; j2 += 64) {
          int eidx = eperm[b0 + j2];
          m = fmaxf(m, lrelu(el_r[esrc_r[eidx]] + ern, 0.2f));
        }
#pragma unroll
        for (int o = 32; o; o >>= 1) m = fmaxf(m, __shfl_xor(m, o));
        for (int c0 = 0; c0 < deg; c0 += 64) {
          int kk = min(64, deg - c0);
          float a = 0.f, cw = 0.f; int sv = 0;
          if (lane < kk) {
            int eidx = eperm[b0 + c0 + lane];
            sv = esrc_r[eidx];
            float e = lrelu(el_r[sv] + ern, 0.2f);
            a = __expf(e - m);
            cw = a * ew_r[eidx];
          }
          ssum += a;
          const int iters = (kk + 1) >> 1;
          for (int jj = 0; jj < iters; jj++) {
            int j = jj * 2 + half;
            float cj = __shfl(cw, j);
            int sj = __shfl(sv, j);
            if (j < kk) {
              uint2 u = *(const uint2*)(h + ((size_t)r * Np + sj) * DD + ql * 4);
              a0 = fmaf(cj, __uint_as_float(u.x << 16), a0);
              a1 = fmaf(cj, __uint_as_float(u.x & 0xFFFF0000u), a1);
              a2 = fmaf(cj, __uint_as_float(u.y << 16), a2);
              a3 = fmaf(cj, __uint_as_float(u.y & 0xFFFF0000u), a3);
            }
          }
        }
#pragma unroll
        for (int o = 32; o; o >>= 1) ssum += __shfl_xor(ssum, o);
      }
    }
    a0 += __shfl_xor(a0, 32); a1 += __shfl_xor(a1, 32);
    a2 += __shfl_xor(a2, 32); a3 += __shfl_xor(a3, 32);
    const float inv = (deg > 0) ? 1.f / ssum : 0.f;
    const float4 bb = *(const float4*)(gb + r * DD + ql * 4);
    float f0 = a0 * inv + bb.x, f1 = a1 * inv + bb.y;
    float f2 = a2 * inv + bb.z, f3 = a3 * inv + bb.w;
    s0 += f0; s1 += f1; s2 += f2; s3 += f3;
    q0 += f0 * f0; q1 += f1 * f1; q2 += f2 * f2; q3 += f3 * f3;
  }
  if (half == 0) {
    *(float4*)(sacc + (size_t)wid * DD + ql * 4) = make_float4(s0, s1, s2, s3);
    *(float4*)(qacc + (size_t)wid * DD + ql * 4) = make_float4(q0, q1, q2, q3);
  }
}

// ---------------- transpose both 128x128 weights ----------------
__global__ void k_transpose2(const float* __restrict__ bw, const float* __restrict__ sw,
                             float* __restrict__ bt, float* __restrict__ st) {
  int i = blockIdx.x * 256 + threadIdx.x;  // 32768
  int m = i >> 14, j = i & 16383;
  int c = j >> 7, k = j & 127;
  if (m) st[k * DD + c] = sw[j];
  else   bt[k * DD + c] = bw[j];
}

// ---------------- combine: dfm/s matvecs + leaky + residual + LayerNorm ----------------
__global__ __launch_bounds__(256) void k_combine(
    const float* __restrict__ sacc, const float* __restrict__ qacc,
    const float* __restrict__ x,
    const float* __restrict__ biT, const float* __restrict__ siT,
    const float* __restrict__ bi_b, const float* __restrict__ si_b,
    const float* __restrict__ res_w, const float* __restrict__ ln_g,
    const float* __restrict__ ln_b,
    float* __restrict__ out, int N)
{
  __shared__ __align__(16) float st[DD][16], dt[DD][16];
  __shared__ float redm[16][2], redq[16][2];
  const int t = threadIdx.x;
  const int c = t & 127, g = t >> 7;
  const int n0 = blockIdx.x * 16;

  float sld[8], dld[8];
#pragma unroll
  for (int it = 0; it < 8; it++) {
    int n = n0 + g * 8 + it;
    float s = 0.f, q = 0.f;
    if (n < N) { s = sacc[(size_t)n * DD + c]; q = qacc[(size_t)n * DD + c]; }
    sld[it] = s;
    dld[it] = 0.5f * (s * s - q);
  }
  *(float4*)&st[c][g * 8]     = *(float4*)&sld[0];
  *(float4*)&st[c][g * 8 + 4] = *(float4*)&sld[4];
  *(float4*)&dt[c][g * 8]     = *(float4*)&dld[0];
  *(float4*)&dt[c][g * 8 + 4] = *(float4*)&dld[4];
  __syncthreads();

  float accB[8], accS[8];
#pragma unroll
  for (int j = 0; j < 8; j++) { accB[j] = 0.f; accS[j] = 0.f; }
  const float* bT = biT + c;
  const float* sT = siT + c;
  for (int k = 0; k < DD; k++) {
    float wb = bT[(size_t)k * DD];
    float ws = sT[(size_t)k * DD];
    float4 d0 = *(const float4*)&dt[k][g * 8];
    float4 d1 = *(const float4*)&dt[k][g * 8 + 4];
    float4 s0 = *(const float4*)&st[k][g * 8];
    float4 s1 = *(const float4*)&st[k][g * 8 + 4];
    accB[0] = fmaf(d0.x, wb, accB[0]); accS[0] = fmaf(s0.x, ws, accS[0]);
    accB[1] = fmaf(d0.y, wb, accB[1]); accS[1] = fmaf(s0.y, ws, accS[1]);
    accB[2] = fmaf(d0.z, wb, accB[2]); accS[2] = fmaf(s0.z, ws, accS[2]);
    accB[3] = fmaf(d0.w, wb, accB[3]); accS[3] = fmaf(s0.w, ws, accS[3]);
    accB[4] = fmaf(d1.x, wb, accB[4]); accS[4] = fmaf(s1.x, ws, accS[4]);
    accB[5] = fmaf(d1.y, wb, accB[5]); accS[5] = fmaf(s1.y, ws, accS[5]);
    accB[6] = fmaf(d1.z, wb, accB[6]); accS[6] = fmaf(s1.z, ws, accS[6]);
    accB[7] = fmaf(d1.w, wb, accB[7]); accS[7] = fmaf(s1.w, ws, accS[7]);
  }

  const float sigw = 1.f / (1.f + __expf(-res_w[0]));
  const float bib = bi_b[c], sib = si_b[c], gg = ln_g[c], bb = ln_b[c];
  float v[8];
#pragma unroll
  for (int j = 0; j < 8; j++) {
    int n = n0 + g * 8 + j;
    float xv = (n < N) ? x[(size_t)n * DD + c] : 0.f;
    float val = lrelu(accB[j] + bib, 0.01f) + lrelu(accS[j] + sib, 0.01f) + xv * sigw;
    v[j] = val;
    float sv = val, sq = val * val;
#pragma unroll
    for (int o = 32; o; o >>= 1) { sv += __shfl_xor(sv, o); sq += __shfl_xor(sq, o); }
    if ((t & 63) == 0) { int w = (t >> 6) & 1; redm[g * 8 + j][w] = sv; redq[g * 8 + j][w] = sq; }
  }
  __syncthreads();
#pragma unroll
  for (int j = 0; j < 8; j++) {
    int n = n0 + g * 8 + j;
    if (n >= N) continue;
    float mu = (redm[g * 8 + j][0] + redm[g * 8 + j][1]) * (1.f / DD);
    float ex2 = (redq[g * 8 + j][0] + redq[g * 8 + j][1]) * (1.f / DD);
    float var = ex2 - mu * mu;
    out[(size_t)n * DD + c] = (v[j] - mu) * rsqrtf(var + 1e-5f) * gg + bb;
  }
}

extern "C" void kernel_launch(void* const* d_in, const int* in_sizes, int n_in,
                              void* d_out, int out_size, void* d_ws, size_t ws_size,
                              hipStream_t stream)
{
  const float* x    = (const float*)d_in[0];
  const int*   esrc = (const int*)d_in[1];
  const int*   edst = (const int*)d_in[2];
  const float* ew   = (const float*)d_in[3];
  const float* W    = (const float*)d_in[4];
  const float* al   = (const float*)d_in[5];
  const float* ar   = (const float*)d_in[6];
  const float* gb   = (const float*)d_in[7];
  const float* bi_w = (const float*)d_in[8];
  const float* bi_b = (const float*)d_in[9];
  const float* si_w = (const float*)d_in[10];
  const float* si_b = (const float*)d_in[11];
  const float* res_w= (const float*)d_in[12];
  const float* ln_g = (const float*)d_in[13];
  const float* ln_b = (const float*)d_in[14];

  const int N = in_sizes[0] / DD;
  const int R = 3;
  const int E = in_sizes[1] / R;
  const int Np = ((N + 127) / 128) * 128;
  const int M = R * N;
  const int NB = (M + 2047) / 2048;

  auto al256 = [](size_t v) { return (v + 255) & ~(size_t)255; };
  char* p = (char*)d_ws;
  // union region: xb [prep_x..mfma]  |  eperm + cnt [hist..node_agg]
  short* xb   = (short*)p;
  int*  eperm = (int*)p;
  int*  cnt   = (int*)(p + al256((size_t)R * E * 4));
  p += al256((size_t)Np * DD * 2);
  short* h    = (short*)p; p += al256((size_t)R * Np * DD * 2);
  float* sacc = (float*)p; p += al256((size_t)Np * DD * 4);
  float* qacc = (float*)p; p += al256((size_t)Np * DD * 4);
  float* el   = (float*)p; p += al256((size_t)M * 4);
  float* er   = (float*)p; p += al256((size_t)M * 4);
  int*   base = (int*)p;   p += al256(((size_t)M + 1) * 4);
  short* WA   = (short*)p; p += al256((size_t)R * 8 * 4 * 64 * 8 * 2);
  float* wl   = (float*)p; p += al256((size_t)R * DD * 4);
  float* wr   = (float*)p; p += al256((size_t)R * DD * 4);
  float* biT  = (float*)p; p += al256((size_t)DD * DD * 4);
  float* siT  = (float*)p; p += al256((size_t)DD * DD * 4);
  int*   bsum = (int*)p;   p += 1024;
  int*   bpre = (int*)p;   p += 1024;

  const int egrid = (E + 255) / 256;

  k_prep_w<<<24, 256, 0, stream>>>(W, WA);
  k_prep_av<<<2, 192, 0, stream>>>(W, al, ar, wl, wr);
  k_transpose2<<<128, 256, 0, stream>>>(bi_w, si_w, biT, siT);
  k_prep_x<<<Np / 16, 256, 0, stream>>>(x, xb, N, Np);
  k_mfma_h<<<Np / 128, 256, 0, stream>>>(xb, WA, wl, wr, h, el, er, N, Np);

  hipMemsetAsync(cnt, 0, (size_t)M * 4, stream);
  k_hist3<<<dim3(egrid, 3), 256, 0, stream>>>(edst, cnt, N, E);
  k_scan_bsum<<<NB, 256, 0, stream>>>(cnt, bsum, M);
  k_scan_btop<<<1, 256, 0, stream>>>(bsum, bpre, NB);
  k_scan_base<<<NB, 256, 0, stream>>>(cnt, bpre, base, M);
  k_scatter3<<<dim3(egrid, 3), 256, 0, stream>>>(edst, base, cnt, eperm, N, E);
  k_node_agg3<<<(N + 3) / 4, 256, 0, stream>>>(base, eperm, esrc, ew, el, er, h, gb,
                                               sacc, qacc, N, Np, E);
  k_combine<<<(N + 15) / 16, 256, 0, stream>>>(
      sacc, qacc, x, biT, siT, bi_b, si_b, res_w, ln_g, ln_b, (float*)d_out, N);
}

// Round 5
// 506.997 us; speedup vs baseline: 7.4689x; 1.2433x over previous
//
#include <hip/hip_runtime.h>

#define DD 128
typedef unsigned int u32;
typedef __attribute__((ext_vector_type(8))) short bf16x8;
typedef __attribute__((ext_vector_type(4))) float f32x4;

__device__ __forceinline__ float lrelu(float v, float s) { return v >= 0.f ? v : s * v; }
__device__ __forceinline__ ushort f2bf(float f) {
  union { float f; u32 u; } v; v.f = f;
  u32 u = v.u;
  return (ushort)((u + 0x7FFFu + ((u >> 16) & 1u)) >> 16);  // RNE
}
__device__ __forceinline__ float bf2f(ushort s) { return __uint_as_float(((u32)s) << 16); }

// ---------------- prep: x (f32) -> bf16 MFMA B-fragment layout ----------------
__global__ __launch_bounds__(256) void k_prep_x(
    const float* __restrict__ x, short* __restrict__ xb, int N, int Np)
{
  int t = blockIdx.x * 256 + threadIdx.x;  // t < Np*16
  int lane = t & 63;
  int n = ((t >> 8) << 4) | (lane & 15);
  int k = ((t >> 6) & 3) * 32 + (lane >> 4) * 8;
  float xv[8];
  if (n < N) {
    float4 a = *(const float4*)(x + (size_t)n * DD + k);
    float4 b = *(const float4*)(x + (size_t)n * DD + k + 4);
    xv[0] = a.x; xv[1] = a.y; xv[2] = a.z; xv[3] = a.w;
    xv[4] = b.x; xv[5] = b.y; xv[6] = b.z; xv[7] = b.w;
  } else {
#pragma unroll
    for (int j = 0; j < 8; j++) xv[j] = 0.f;
  }
  uint4 st;
  st.x = (u32)f2bf(xv[0]) | ((u32)f2bf(xv[1]) << 16);
  st.y = (u32)f2bf(xv[2]) | ((u32)f2bf(xv[3]) << 16);
  st.z = (u32)f2bf(xv[4]) | ((u32)f2bf(xv[5]) << 16);
  st.w = (u32)f2bf(xv[6]) | ((u32)f2bf(xv[7]) << 16);
  *(uint4*)(xb + (size_t)t * 8) = st;
}

// ---------------- prep: W^T -> bf16 MFMA A-fragment layout ----------------
__global__ __launch_bounds__(256) void k_prep_w(const float* __restrict__ W,
                                                short* __restrict__ WA)
{
  int t = blockIdx.x * 256 + threadIdx.x;  // 6144
  int lane = t & 63, ks = (t >> 6) & 3, cf = (t >> 8) & 7, r = t >> 11;
  int c = cf * 16 + (lane & 15);
  int kb = ks * 32 + (lane >> 4) * 8;
  const float* Wr = W + (size_t)r * DD * DD;
  ushort o[8];
#pragma unroll
  for (int j = 0; j < 8; j++) o[j] = f2bf(Wr[(size_t)(kb + j) * DD + c]);
  uint4 st;
  st.x = (u32)o[0] | ((u32)o[1] << 16);
  st.y = (u32)o[2] | ((u32)o[3] << 16);
  st.z = (u32)o[4] | ((u32)o[5] << 16);
  st.w = (u32)o[6] | ((u32)o[7] << 16);
  *(uint4*)(WA + (size_t)t * 8) = st;
}

// ---------------- prep: bi_w/si_w -> bf16 A-frags (row-major, no transpose) ----------------
__global__ __launch_bounds__(256) void k_prep_cw(const float* __restrict__ bw,
                                                 const float* __restrict__ sw,
                                                 short* __restrict__ WB)
{
  int t = blockIdx.x * 256 + threadIdx.x;  // 4096
  int lane = t & 63, ks = (t >> 6) & 3, cf = (t >> 8) & 7, m = t >> 11;
  const float* src = m ? sw : bw;
  int c = cf * 16 + (lane & 15);
  int k = ks * 32 + (lane >> 4) * 8;
  const float* pr = src + (size_t)c * DD + k;
  uint4 st;
  st.x = (u32)f2bf(pr[0]) | ((u32)f2bf(pr[1]) << 16);
  st.y = (u32)f2bf(pr[2]) | ((u32)f2bf(pr[3]) << 16);
  st.z = (u32)f2bf(pr[4]) | ((u32)f2bf(pr[5]) << 16);
  st.w = (u32)f2bf(pr[6]) | ((u32)f2bf(pr[7]) << 16);
  *(uint4*)(WB + (size_t)t * 8) = st;
}

// ---------------- prep: wl = W @ attn_l, wr = W @ attn_r (per relation) ----------------
__global__ void k_prep_av(const float* __restrict__ W, const float* __restrict__ al,
                          const float* __restrict__ ar, float* __restrict__ wl,
                          float* __restrict__ wr)
{
  int t = blockIdx.x * 192 + threadIdx.x;  // 384
  if (t >= 384) return;
  int r = t >> 7, k = t & 127;
  const float* Wrow = W + (size_t)r * DD * DD + (size_t)k * DD;
  const float* alr = al + r * DD;
  const float* arr = ar + r * DD;
  float pl = 0.f, pr = 0.f;
  for (int c = 0; c < DD; c++) { float w = Wrow[c]; pl = fmaf(w, alr[c], pl); pr = fmaf(w, arr[c], pr); }
  wl[t] = pl; wr[t] = pr;
}

// ---------------- MFMA: h = x@W (all 3 relations), el/er epilogue ----------------
__global__ __launch_bounds__(256) void k_mfma_h(
    const short* __restrict__ xb, const short* __restrict__ WA,
    const float* __restrict__ wl, const float* __restrict__ wr,
    short* __restrict__ h, float* __restrict__ el, float* __restrict__ er,
    int N, int Np)
{
  const int lane = threadIdx.x & 63;
  const int w = threadIdx.x >> 6;
  const int n0 = blockIdx.x * 128 + w * 32;
  const int rb = n0 >> 4;

  bf16x8 xf[2][4];
#pragma unroll
  for (int nf = 0; nf < 2; nf++)
#pragma unroll
    for (int ks = 0; ks < 4; ks++)
      xf[nf][ks] = *(const bf16x8*)(xb + (((size_t)(rb + nf) * 4 + ks) * 64 + lane) * 8);

  for (int r = 0; r < 3; r++) {
    f32x4 acc[2][8];
#pragma unroll
    for (int nf = 0; nf < 2; nf++)
#pragma unroll
      for (int cf = 0; cf < 8; cf++) acc[nf][cf] = (f32x4){0.f, 0.f, 0.f, 0.f};

#pragma unroll
    for (int ks = 0; ks < 4; ks++) {
      bf16x8 af[8];
#pragma unroll
      for (int cf = 0; cf < 8; cf++)
        af[cf] = *(const bf16x8*)(WA + ((((size_t)r * 8 + cf) * 4 + ks) * 64 + lane) * 8);
#pragma unroll
      for (int nf = 0; nf < 2; nf++)
#pragma unroll
        for (int cf = 0; cf < 8; cf++)
          acc[nf][cf] = __builtin_amdgcn_mfma_f32_16x16x32_bf16(af[cf], xf[nf][ks],
                                                                acc[nf][cf], 0, 0, 0);
    }

#pragma unroll
    for (int nf = 0; nf < 2; nf++) {
      int node = n0 + nf * 16 + (lane & 15);
      if (node < N) {
        size_t rowoff = ((size_t)r * Np + node) * DD + (lane >> 4) * 4;
#pragma unroll
        for (int cf = 0; cf < 8; cf++) {
          uint2 uu;
          uu.x = (u32)f2bf(acc[nf][cf][0]) | ((u32)f2bf(acc[nf][cf][1]) << 16);
          uu.y = (u32)f2bf(acc[nf][cf][2]) | ((u32)f2bf(acc[nf][cf][3]) << 16);
          *(uint2*)(h + rowoff + cf * 16) = uu;
        }
      }
    }

#pragma unroll
    for (int nf = 0; nf < 2; nf++) {
      float pl = 0.f, pr = 0.f;
#pragma unroll
      for (int ks = 0; ks < 4; ks++) {
        const float* wlp = wl + r * DD + ks * 32 + (lane >> 4) * 8;
        const float* wrp = wr + r * DD + ks * 32 + (lane >> 4) * 8;
#pragma unroll
        for (int j = 0; j < 8; j++) {
          float xv = bf2f((ushort)xf[nf][ks][j]);
          pl = fmaf(xv, wlp[j], pl);
          pr = fmaf(xv, wrp[j], pr);
        }
      }
      pl += __shfl_xor(pl, 16); pl += __shfl_xor(pl, 32);
      pr += __shfl_xor(pr, 16); pr += __shfl_xor(pr, 32);
      int node = n0 + nf * 16 + lane;
      if (lane < 16 && node < N) {
        el[(size_t)r * N + node] = pl;
        er[(size_t)r * N + node] = pr;
      }
    }
  }
}

// ---------------- CSR build: histogram of dst (grid.y = r) ----------------
__global__ void k_hist3(const int* __restrict__ dst, int* __restrict__ cnt, int N, int E) {
  int i = blockIdx.x * 256 + threadIdx.x;
  int r = blockIdx.y;
  if (i < E) atomicAdd(cnt + (size_t)r * N + dst[(size_t)r * E + i], 1);
}

// ---------------- hierarchical scan: base[0..M] ----------------
__global__ __launch_bounds__(256) void k_scan_bsum(const int* __restrict__ cnt,
                                                   int* __restrict__ bsum, int M)
{
  __shared__ int red[256];
  const int t = threadIdx.x;
  const int g0 = blockIdx.x * 2048 + t * 8;
  int s = 0;
#pragma unroll
  for (int j = 0; j < 8; j++) { int i = g0 + j; if (i < M) s += cnt[i]; }
  red[t] = s;
  __syncthreads();
  for (int o = 128; o; o >>= 1) {
    if (t < o) red[t] += red[t + o];
    __syncthreads();
  }
  if (t == 0) bsum[blockIdx.x] = red[0];
}

__global__ __launch_bounds__(256) void k_scan_btop(const int* __restrict__ bsum,
                                                   int* __restrict__ bpre, int NB)
{
  __shared__ int sums[256];
  const int t = threadIdx.x;
  int v = (t < NB) ? bsum[t] : 0;
  sums[t] = v;
  __syncthreads();
  for (int o = 1; o < 256; o <<= 1) {
    int u = (t >= o) ? sums[t - o] : 0;
    __syncthreads();
    sums[t] += u;
    __syncthreads();
  }
  if (t < NB) bpre[t] = sums[t] - v;
}

__global__ __launch_bounds__(256) void k_scan_base(const int* __restrict__ cnt,
    const int* __restrict__ bpre, int* __restrict__ base, int M)
{
  __shared__ int sums[256];
  const int t = threadIdx.x;
  const int g0 = blockIdx.x * 2048 + t * 8;
  int c[8];
  int ts = 0;
#pragma unroll
  for (int j = 0; j < 8; j++) { int i = g0 + j; c[j] = (i < M) ? cnt[i] : 0; ts += c[j]; }
  sums[t] = ts;
  __syncthreads();
  for (int o = 1; o < 256; o <<= 1) {
    int u = (t >= o) ? sums[t - o] : 0;
    __syncthreads();
    sums[t] += u;
    __syncthreads();
  }
  int run = bpre[blockIdx.x] + sums[t] - ts;
#pragma unroll
  for (int j = 0; j < 8; j++) {
    int i = g0 + j;
    if (i <= M) base[i] = run;
    run += c[j];
  }
}

// ---------------- scatter: CSR edge-index permutation only ----------------
__global__ void k_scatter3(const int* __restrict__ dst, const int* __restrict__ base,
                           int* __restrict__ cnt, int* __restrict__ eperm, int N, int E)
{
  int i = blockIdx.x * 256 + threadIdx.x;
  if (i >= E) return;
  int r = blockIdx.y;
  size_t node = (size_t)r * N + dst[(size_t)r * E + i];
  int pos = base[node] + (atomicSub(cnt + node, 1) - 1);
  eperm[pos] = i;
}

// ---------------- fused per-node softmax+aggregate, all 3 relations ----------------
// outputs s and dfm=0.5(s^2-q) as bf16 rows (MFMA-ready for combine)
__global__ __launch_bounds__(256) void k_node_agg3(
    const int* __restrict__ base, const int* __restrict__ eperm,
    const int* __restrict__ esrc, const float* __restrict__ ew,
    const float* __restrict__ el, const float* __restrict__ er,
    const short* __restrict__ h, const float* __restrict__ gb,
    short* __restrict__ sb, short* __restrict__ db, int N, int Np, int E)
{
  const int wid = (int)(((long long)blockIdx.x * 256 + threadIdx.x) >> 6);
  const int lane = threadIdx.x & 63;
  if (wid >= N) return;
  const int ql = lane & 31, half = lane >> 5;

  float s0 = 0, s1 = 0, s2 = 0, s3 = 0, q0 = 0, q1 = 0, q2 = 0, q3 = 0;

  for (int r = 0; r < 3; r++) {
    const int nid = r * N + wid;
    const int b0 = base[nid];
    const int deg = base[nid + 1] - b0;
    const int* esrc_r = esrc + (size_t)r * E;
    const float* ew_r = ew + (size_t)r * E;
    const float* el_r = el + (size_t)r * N;
    float a0 = 0, a1 = 0, a2 = 0, a3 = 0, ssum = 0.f;

    if (deg > 0) {
      const float ern = er[nid];
      if (deg <= 64) {
        float e = -1e30f, cw = 0.f; int sv = 0;
        if (lane < deg) {
          int eidx = eperm[b0 + lane];
          sv = esrc_r[eidx];
          e = lrelu(el_r[sv] + ern, 0.2f);
          cw = ew_r[eidx];
        }
        float m = e;
#pragma unroll
        for (int o = 32; o; o >>= 1) m = fmaxf(m, __shfl_xor(m, o));
        float a = 0.f;
        if (lane < deg) { a = __expf(e - m); cw *= a; }
        ssum = a;
#pragma unroll
        for (int o = 32; o; o >>= 1) ssum += __shfl_xor(ssum, o);
        const int iters = (deg + 1) >> 1;
        for (int jj = 0; jj < iters; jj++) {
          int j = jj * 2 + half;
          float cj = __shfl(cw, j);
          int sj = __shfl(sv, j);
          if (j < deg) {
            uint2 u = *(const uint2*)(h + ((size_t)r * Np + sj) * DD + ql * 4);
            a0 = fmaf(cj, __uint_as_float(u.x << 16), a0);
            a1 = fmaf(cj, __uint_as_float(u.x & 0xFFFF0000u), a1);
            a2 = fmaf(cj, __uint_as_float(u.y << 16), a2);
            a3 = fmaf(cj, __uint_as_float(u.y & 0xFFFF0000u), a3);
          }
        }
      } else {
        float m = -1e30f;
        for (int j2 = lane; j2 < deg; j2 += 64) {
          int eidx = eperm[b0 + j2];
          m = fmaxf(m, lrelu(el_r[esrc_r[eidx]] + ern, 0.2f));
        }
#pragma unroll
        for (int o = 32; o; o >>= 1) m = fmaxf(m, __shfl_xor(m, o));
        for (int c0 = 0; c0 < deg; c0 += 64) {
          int kk = min(64, deg - c0);
          float a = 0.f, cw = 0.f; int sv = 0;
          if (lane < kk) {
            int eidx = eperm[b0 + c0 + lane];
            sv = esrc_r[eidx];
            float e = lrelu(el_r[sv] + ern, 0.2f);
            a = __expf(e - m);
            cw = a * ew_r[eidx];
          }
          ssum += a;
          const int iters = (kk + 1) >> 1;
          for (int jj = 0; jj < iters; jj++) {
            int j = jj * 2 + half;
            float cj = __shfl(cw, j);
            int sj = __shfl(sv, j);
            if (j < kk) {
              uint2 u = *(const uint2*)(h + ((size_t)r * Np + sj) * DD + ql * 4);
              a0 = fmaf(cj, __uint_as_float(u.x << 16), a0);
              a1 = fmaf(cj, __uint_as_float(u.x & 0xFFFF0000u), a1);
              a2 = fmaf(cj, __uint_as_float(u.y << 16), a2);
              a3 = fmaf(cj, __uint_as_float(u.y & 0xFFFF0000u), a3);
            }
          }
        }
#pragma unroll
        for (int o = 32; o; o >>= 1) ssum += __shfl_xor(ssum, o);
      }
    }
    a0 += __shfl_xor(a0, 32); a1 += __shfl_xor(a1, 32);
    a2 += __shfl_xor(a2, 32); a3 += __shfl_xor(a3, 32);
    const float inv = (deg > 0) ? 1.f / ssum : 0.f;
    const float4 bb = *(const float4*)(gb + r * DD + ql * 4);
    float f0 = a0 * inv + bb.x, f1 = a1 * inv + bb.y;
    float f2 = a2 * inv + bb.z, f3 = a3 * inv + bb.w;
    s0 += f0; s1 += f1; s2 += f2; s3 += f3;
    q0 += f0 * f0; q1 += f1 * f1; q2 += f2 * f2; q3 += f3 * f3;
  }
  if (half == 0) {
    float d0 = 0.5f * (s0 * s0 - q0), d1 = 0.5f * (s1 * s1 - q1);
    float d2 = 0.5f * (s2 * s2 - q2), d3 = 0.5f * (s3 * s3 - q3);
    uint2 us, ud;
    us.x = (u32)f2bf(s0) | ((u32)f2bf(s1) << 16);
    us.y = (u32)f2bf(s2) | ((u32)f2bf(s3) << 16);
    ud.x = (u32)f2bf(d0) | ((u32)f2bf(d1) << 16);
    ud.y = (u32)f2bf(d2) | ((u32)f2bf(d3) << 16);
    *(uint2*)(sb + (size_t)wid * DD + ql * 4) = us;
    *(uint2*)(db + (size_t)wid * DD + ql * 4) = ud;
  }
}

// ---------------- combine via MFMA: nfm = leaky(dfm@biW^T)+leaky(s@siW^T)+res, LN ----------------
// 4 waves x 32 nodes per block; no LDS.
__global__ __launch_bounds__(256) void k_combine_mfma(
    const short* __restrict__ sb, const short* __restrict__ db,
    const float* __restrict__ x, const short* __restrict__ WB,
    const float* __restrict__ bi_b, const float* __restrict__ si_b,
    const float* __restrict__ res_w, const float* __restrict__ ln_g,
    const float* __restrict__ ln_b, float* __restrict__ out, int N)
{
  const int lane = threadIdx.x & 63;
  const int w = threadIdx.x >> 6;
  const int n0 = blockIdx.x * 128 + w * 32;
  const float sigw = 1.f / (1.f + __expf(-res_w[0]));
  const int fh4 = (lane >> 4) << 2;  // (l>>4)*4

  for (int nf = 0; nf < 2; nf++) {
    const int node = n0 + nf * 16 + (lane & 15);
    const size_t rowo = (size_t)node * DD + ((lane >> 4) << 3);
    bf16x8 sf[4], df[4];
#pragma unroll
    for (int ks = 0; ks < 4; ks++) {
      sf[ks] = *(const bf16x8*)(sb + rowo + ks * 32);
      df[ks] = *(const bf16x8*)(db + rowo + ks * 32);
    }
    f32x4 accB[8], accS[8];
#pragma unroll
    for (int cf = 0; cf < 8; cf++) {
      accB[cf] = (f32x4){0.f, 0.f, 0.f, 0.f};
      accS[cf] = (f32x4){0.f, 0.f, 0.f, 0.f};
    }
#pragma unroll
    for (int ks = 0; ks < 4; ks++) {
#pragma unroll
      for (int cf = 0; cf < 8; cf++) {
        bf16x8 ab = *(const bf16x8*)(WB + ((((size_t)0 * 8 + cf) * 4 + ks) * 64 + lane) * 8);
        bf16x8 as = *(const bf16x8*)(WB + ((((size_t)1 * 8 + cf) * 4 + ks) * 64 + lane) * 8);
        accB[cf] = __builtin_amdgcn_mfma_f32_16x16x32_bf16(ab, df[ks], accB[cf], 0, 0, 0);
        accS[cf] = __builtin_amdgcn_mfma_f32_16x16x32_bf16(as, sf[ks], accS[cf], 0, 0, 0);
      }
    }

    float vals[8][4];
    float sv = 0.f, sq = 0.f;
#pragma unroll
    for (int cf = 0; cf < 8; cf++) {
      int c0 = cf * 16 + fh4;
      float4 bb4 = *(const float4*)(bi_b + c0);
      float4 sb4 = *(const float4*)(si_b + c0);
      float4 xv = make_float4(0.f, 0.f, 0.f, 0.f);
      if (node < N) xv = *(const float4*)(x + (size_t)node * DD + c0);
      const float* bbp = (const float*)&bb4;
      const float* sbp = (const float*)&sb4;
      const float* xvp = (const float*)&xv;
#pragma unroll
      for (int j = 0; j < 4; j++) {
        float val = lrelu(accB[cf][j] + bbp[j], 0.01f)
                  + lrelu(accS[cf][j] + sbp[j], 0.01f)
                  + xvp[j] * sigw;
        vals[cf][j] = val;
        sv += val; sq += val * val;
      }
    }
    sv += __shfl_xor(sv, 16); sq += __shfl_xor(sq, 16);
    sv += __shfl_xor(sv, 32); sq += __shfl_xor(sq, 32);
    const float mu = sv * (1.f / DD);
    const float var = sq * (1.f / DD) - mu * mu;
    const float rs = rsqrtf(var + 1e-5f);
    if (node < N) {
#pragma unroll
      for (int cf = 0; cf < 8; cf++) {
        int c0 = cf * 16 + fh4;
        float4 g4 = *(const float4*)(ln_g + c0);
        float4 b4 = *(const float4*)(ln_b + c0);
        float4 o;
        o.x = (vals[cf][0] - mu) * rs * g4.x + b4.x;
        o.y = (vals[cf][1] - mu) * rs * g4.y + b4.y;
        o.z = (vals[cf][2] - mu) * rs * g4.z + b4.z;
        o.w = (vals[cf][3] - mu) * rs * g4.w + b4.w;
        *(float4*)(out + (size_t)node * DD + c0) = o;
      }
    }
  }
}

extern "C" void kernel_launch(void* const* d_in, const int* in_sizes, int n_in,
                              void* d_out, int out_size, void* d_ws, size_t ws_size,
                              hipStream_t stream)
{
  const float* x    = (const float*)d_in[0];
  const int*   esrc = (const int*)d_in[1];
  const int*   edst = (const int*)d_in[2];
  const float* ew   = (const float*)d_in[3];
  const float* W    = (const float*)d_in[4];
  const float* al   = (const float*)d_in[5];
  const float* ar   = (const float*)d_in[6];
  const float* gb   = (const float*)d_in[7];
  const float* bi_w = (const float*)d_in[8];
  const float* bi_b = (const float*)d_in[9];
  const float* si_w = (const float*)d_in[10];
  const float* si_b = (const float*)d_in[11];
  const float* res_w= (const float*)d_in[12];
  const float* ln_g = (const float*)d_in[13];
  const float* ln_b = (const float*)d_in[14];

  const int N = in_sizes[0] / DD;
  const int R = 3;
  const int E = in_sizes[1] / R;
  const int Np = ((N + 127) / 128) * 128;
  const int M = R * N;
  const int NB = (M + 2047) / 2048;

  auto al256 = [](size_t v) { return (v + 255) & ~(size_t)255; };
  char* p = (char*)d_ws;
  // union region: xb [prep_x..mfma]  |  eperm + cnt [hist..node_agg]
  short* xb   = (short*)p;
  int*  eperm = (int*)p;
  int*  cnt   = (int*)(p + al256((size_t)R * E * 4));
  p += al256((size_t)Np * DD * 2);
  short* h    = (short*)p; p += al256((size_t)R * Np * DD * 2);
  short* sbuf = (short*)p; p += al256((size_t)Np * DD * 2);
  short* dbuf = (short*)p; p += al256((size_t)Np * DD * 2);
  float* el   = (float*)p; p += al256((size_t)M * 4);
  float* er   = (float*)p; p += al256((size_t)M * 4);
  int*   base = (int*)p;   p += al256(((size_t)M + 1) * 4);
  short* WA   = (short*)p; p += al256((size_t)R * 8 * 4 * 64 * 8 * 2);
  short* WB   = (short*)p; p += al256((size_t)2 * 8 * 4 * 64 * 8 * 2);
  float* wl   = (float*)p; p += al256((size_t)R * DD * 4);
  float* wr   = (float*)p; p += al256((size_t)R * DD * 4);
  int*   bsum = (int*)p;   p += 1024;
  int*   bpre = (int*)p;   p += 1024;

  const int egrid = (E + 255) / 256;

  k_prep_w<<<24, 256, 0, stream>>>(W, WA);
  k_prep_cw<<<16, 256, 0, stream>>>(bi_w, si_w, WB);
  k_prep_av<<<2, 192, 0, stream>>>(W, al, ar, wl, wr);
  k_prep_x<<<Np / 16, 256, 0, stream>>>(x, xb, N, Np);
  k_mfma_h<<<Np / 128, 256, 0, stream>>>(xb, WA, wl, wr, h, el, er, N, Np);

  hipMemsetAsync(cnt, 0, (size_t)M * 4, stream);
  k_hist3<<<dim3(egrid, 3), 256, 0, stream>>>(edst, cnt, N, E);
  k_scan_bsum<<<NB, 256, 0, stream>>>(cnt, bsum, M);
  k_scan_btop<<<1, 256, 0, stream>>>(bsum, bpre, NB);
  k_scan_base<<<NB, 256, 0, stream>>>(cnt, bpre, base, M);
  k_scatter3<<<dim3(egrid, 3), 256, 0, stream>>>(edst, base, cnt, eperm, N, E);
  k_node_agg3<<<(N + 3) / 4, 256, 0, stream>>>(base, eperm, esrc, ew, el, er, h, gb,
                                               sbuf, dbuf, N, Np, E);
  k_combine_mfma<<<Np / 128, 256, 0, stream>>>(
      sbuf, dbuf, x, WB, bi_b, si_b, res_w, ln_g, ln_b, (float*)d_out, N);
}